// Round 4
// baseline (253.407 us; speedup 1.0000x reference)
//
#include <hip/hip_runtime.h>

typedef unsigned short u16;
typedef __bf16 bf16x8 __attribute__((ext_vector_type(8)));
typedef float f32x4 __attribute__((ext_vector_type(4)));

union B8 { uint4 u; bf16x8 v; };
union U8 { u16 s[8]; uint4 u; };

#define NB 16
#define NQ 2048
#define NK 2048
#define ND 128

template<int C>
__device__ __forceinline__ float dppf(float x) {
  int v = __builtin_bit_cast(int, x);
  int r = __builtin_amdgcn_update_dpp(v, v, C, 0xF, 0xF, true);
  return __builtin_bit_cast(float, r);
}
// reduce across each 16-lane DPP row; all lanes get the result
__device__ __forceinline__ float rowmax16(float x) {
  x = fmaxf(x, dppf<0xB1>(x));   // quad_perm xor1
  x = fmaxf(x, dppf<0x4E>(x));   // quad_perm xor2
  x = fmaxf(x, dppf<0x141>(x));  // row_half_mirror (== xor4 after xor1,xor2)
  x = fmaxf(x, dppf<0x140>(x));  // row_mirror      (== xor8 after the above)
  return x;
}
__device__ __forceinline__ float rowsum16(float x) {
  x += dppf<0xB1>(x);
  x += dppf<0x4E>(x);
  x += dppf<0x141>(x);
  x += dppf<0x140>(x);
  return x;
}

__device__ __forceinline__ bf16x8 cvt8(float4 a, float4 b) {
  bf16x8 r;
  r[0] = (__bf16)a.x; r[1] = (__bf16)a.y; r[2] = (__bf16)a.z; r[3] = (__bf16)a.w;
  r[4] = (__bf16)b.x; r[5] = (__bf16)b.y; r[6] = (__bf16)b.z; r[7] = (__bf16)b.w;
  return r;
}

// Flash attention fwd. fp32 I/O, bf16 MFMA compute.
// 2 waves/block, Q-tile 64 (32 rows/wave), K-tile 64.
__global__ __launch_bounds__(128, 1)
void flash_fwd(const float* __restrict__ qg, const float* __restrict__ kg,
               const float* __restrict__ vg, const int* __restrict__ vlg,
               float* __restrict__ og)
{
  // K tile (bf16): 64 rows x 128 d, granule(8elem)-XOR swizzled: (row,g) at row*128+(g^(row&15))*8
  __shared__ __align__(16) u16 sK[2][64 * 128];
  // V tile (bf16) d-major: 128 d-rows x 64 kv: (d,kv) at d*64+((kv>>3)^(d&7))*8+(kv&7)
  __shared__ __align__(16) u16 sV[2][128 * 64];
  // P scratch per wave: 32 rows x 72 (pad) bf16
  __shared__ __align__(16) u16 sP[2][32 * 72];

  const int tid  = threadIdx.x;
  const int lane = tid & 63;
  const int wv   = tid >> 6;     // wave 0..1
  const int n    = lane & 15;
  const int quad = lane >> 4;

  const int bi = blockIdx.x;
  // XCD-swizzle: blocks with same (bi&7) land on same XCD -> 2 batches/XCD L2
  const int b  = ((bi & 7) << 1) | (bi >> 8);
  const int qt = (bi >> 3) & 31;

  const int vl = vlg[b];
  const int nt = (vl + 63) >> 6;

  const int qrow0 = qt * 64 + wv * 32;

  // Q fragments (bf16), kept in registers across whole K loop.
  // A-frag convention: A[m=lane&15][k=quad*8+j] (self-consistent with B-frags)
  bf16x8 qf[2][4];
  #pragma unroll
  for (int mb = 0; mb < 2; ++mb)
    #pragma unroll
    for (int c = 0; c < 4; ++c) {
      const float* qp = qg + (size_t)(b * NQ + qrow0 + mb * 16 + n) * ND
                        + c * 32 + quad * 8;
      qf[mb][c] = cvt8(*(const float4*)qp, *(const float4*)(qp + 4));
    }

  f32x4 O[2][8];
  float mst[2][4], lst[2][4];
  #pragma unroll
  for (int mb = 0; mb < 2; ++mb) {
    #pragma unroll
    for (int f = 0; f < 8; ++f) O[mb][f] = (f32x4){0.f, 0.f, 0.f, 0.f};
    #pragma unroll
    for (int r = 0; r < 4; ++r) { mst[mb][r] = -__builtin_inff(); lst[mb][r] = 0.f; }
  }

  const float* kb = kg + (size_t)(b * NK) * ND;
  const float* vb = vg + (size_t)(b * NK) * ND;

  // Staging registers (bf16, converted right after load)
  bf16x8 kb16[8];   // thread owns K row tid>>1, cols (tid&1)*64 .. +63
  bf16x8 vb16[8];   // lane owns V row lane,   cols wv*64 .. +63

  auto kload = [&](int t) {
    const float* src = kb + (size_t)(t * 64 + (tid >> 1)) * ND + (tid & 1) * 64;
    #pragma unroll
    for (int c = 0; c < 8; ++c)
      kb16[c] = cvt8(*(const float4*)(src + c * 8), *(const float4*)(src + c * 8 + 4));
  };
  auto kstore = [&](int buf) {
    const int r = tid >> 1, h = tid & 1;
    #pragma unroll
    for (int c = 0; c < 8; ++c) {
      B8 tt; tt.v = kb16[c];
      *(uint4*)(&sK[buf][r * 128 + (((h * 8 + c) ^ (r & 15)) << 3)]) = tt.u;
    }
  };
  auto vload = [&](int t) {
    const float* src = vb + (size_t)(t * 64 + lane) * ND + wv * 64;
    #pragma unroll
    for (int c = 0; c < 8; ++c)
      vb16[c] = cvt8(*(const float4*)(src + c * 8), *(const float4*)(src + c * 8 + 4));
  };
  auto vstore = [&](int buf) {
    #pragma unroll
    for (int c = 0; c < 8; ++c) {
      B8 x; x.v = vb16[c];
      U8 tt; tt.u = x.u;
      const int dbase = wv * 64 + c * 8;   // dbase%8==0 -> d&7 == j
      #pragma unroll
      for (int j = 0; j < 8; ++j) {
        int dd = dbase + j;
        sV[buf][dd * 64 + (((lane >> 3) ^ j) << 3) + (lane & 7)] = tt.s[j];
      }
    }
  };

  kload(0);
  vload(0);

  constexpr float CEXP = 0.08838834764831845f * 1.44269504088896340f; // log2e/sqrt(128)

  for (int t = 0; t < nt; ++t) {
    const int buf = t & 1;
    kstore(buf);                 // regs(t) -> LDS  (other wave may read buf^1: disjoint)
    vstore(buf);
    __syncthreads();             // LDS(t) visible to both waves
    if (t + 1 < nt) {            // issue global loads for t+1; land in regs during compute
      kload(t + 1);
      vload(t + 1);
    }

    const u16* Kb = sK[buf];
    const u16* Vb = sV[buf];

    // ---- S = Q * K^T  (32 MFMAs, 16 b128 LDS reads) ----
    f32x4 S[2][4];
    #pragma unroll
    for (int mb = 0; mb < 2; ++mb)
      #pragma unroll
      for (int jn = 0; jn < 4; ++jn) S[mb][jn] = (f32x4){0.f, 0.f, 0.f, 0.f};

    #pragma unroll
    for (int c = 0; c < 4; ++c) {
      #pragma unroll
      for (int jn = 0; jn < 4; ++jn) {
        B8 bb;   // B-frag: K[col=jn*16+n][d = c*32+quad*8+j], unswizzle granule
        bb.u = *(const uint4*)(Kb + (jn * 16 + n) * 128 + (((c * 4 + quad) ^ n) * 8));
        #pragma unroll
        for (int mb = 0; mb < 2; ++mb)
          S[mb][jn] = __builtin_amdgcn_mfma_f32_16x16x32_bf16(qf[mb][c], bb.v, S[mb][jn], 0, 0, 0);
      }
    }

    // ---- mask tail columns (kv >= vl) ----
    if (t * 64 + 64 > vl) {
      #pragma unroll
      for (int jn = 0; jn < 4; ++jn) {
        bool msk = (t * 64 + jn * 16 + n) >= vl;
        #pragma unroll
        for (int mb = 0; mb < 2; ++mb)
          #pragma unroll
          for (int r = 0; r < 4; ++r)
            S[mb][jn][r] = msk ? -1e30f : S[mb][jn][r];
      }
    }

    // ---- online softmax (row = quad*4+r, 16 cols across lanes n) ----
    #pragma unroll
    for (int mb = 0; mb < 2; ++mb) {
      float al[4];
      #pragma unroll
      for (int r = 0; r < 4; ++r) {
        float mx = fmaxf(fmaxf(S[mb][0][r], S[mb][1][r]),
                         fmaxf(S[mb][2][r], S[mb][3][r]));
        mx = rowmax16(mx);
        float mnew = fmaxf(mst[mb][r], mx);
        float a = __builtin_exp2f((mst[mb][r] - mnew) * CEXP);
        mst[mb][r] = mnew;
        float ssum = 0.f;
        #pragma unroll
        for (int jn = 0; jn < 4; ++jn) {
          float p = __builtin_exp2f((S[mb][jn][r] - mnew) * CEXP);
          S[mb][jn][r] = p;
          ssum += p;
        }
        ssum = rowsum16(ssum);
        lst[mb][r] = lst[mb][r] * a + ssum;
        al[r] = a;
      }
      #pragma unroll
      for (int f = 0; f < 8; ++f) {
        O[mb][f][0] *= al[0]; O[mb][f][1] *= al[1];
        O[mb][f][2] *= al[2]; O[mb][f][3] *= al[3];
      }
      // P (C-layout) -> per-wave LDS; same-wave DS ops are in-order, and the
      // may-alias sP reads below can't be hoisted above these writes.
      #pragma unroll
      for (int jn = 0; jn < 4; ++jn)
        #pragma unroll
        for (int r = 0; r < 4; ++r) {
          __bf16 h = (__bf16)S[mb][jn][r];
          sP[wv][(mb * 16 + quad * 4 + r) * 72 + jn * 16 + n] = __builtin_bit_cast(u16, h);
        }
    }

    // ---- O += P * V  (32 MFMAs) ----
    #pragma unroll
    for (int kc = 0; kc < 2; ++kc) {
      bf16x8 af[2];
      #pragma unroll
      for (int mb = 0; mb < 2; ++mb) {
        B8 tt;
        tt.u = *(const uint4*)(&sP[wv][(mb * 16 + n) * 72 + kc * 32 + quad * 8]);
        af[mb] = tt.v;
      }
      #pragma unroll
      for (int f = 0; f < 8; ++f) {
        int d = f * 16 + n;
        B8 bb;  // B-frag: sV[d][kv = kc*32+quad*8+j], unswizzle granule
        bb.u = *(const uint4*)(Vb + d * 64 + (((kc * 4 + quad) ^ (d & 7)) * 8));
        #pragma unroll
        for (int mb = 0; mb < 2; ++mb)
          O[mb][f] = __builtin_amdgcn_mfma_f32_16x16x32_bf16(af[mb], bb.v, O[mb][f], 0, 0, 0);
      }
    }
  }

  // ---- epilogue: O / l, store fp32 ----
  #pragma unroll
  for (int mb = 0; mb < 2; ++mb)
    #pragma unroll
    for (int r = 0; r < 4; ++r) {
      float rl = 1.0f / lst[mb][r];
      int qrow = qrow0 + mb * 16 + quad * 4 + r;
      float* op = og + (size_t)(b * NQ + qrow) * ND + n;
      #pragma unroll
      for (int f = 0; f < 8; ++f)
        op[f * 16] = O[mb][f][r] * rl;
    }
}

extern "C" void kernel_launch(void* const* d_in, const int* in_sizes, int n_in,
                              void* d_out, int out_size, void* d_ws, size_t ws_size,
                              hipStream_t stream) {
  const float* q  = (const float*)d_in[0];
  const float* k  = (const float*)d_in[1];
  const float* v  = (const float*)d_in[2];
  const int*  vl  = (const int*)d_in[3];
  float* out = (float*)d_out;
  (void)d_ws; (void)ws_size;

  hipLaunchKernelGGL(flash_fwd, dim3(512), dim3(128), 0, stream, q, k, v, vl, out);
}

// Round 5
// 234.299 us; speedup vs baseline: 1.0816x; 1.0816x over previous
//
#include <hip/hip_runtime.h>

typedef unsigned short u16;
typedef __bf16 bf16x8 __attribute__((ext_vector_type(8)));
typedef float f32x4 __attribute__((ext_vector_type(4)));

union B8 { uint4 u; bf16x8 v; };
union U8 { u16 s[8]; uint4 u; };

#define NB 16
#define NQ 2048
#define NK 2048
#define ND 128

template<int C>
__device__ __forceinline__ float dppf(float x) {
  int v = __builtin_bit_cast(int, x);
  int r = __builtin_amdgcn_update_dpp(v, v, C, 0xF, 0xF, true);
  return __builtin_bit_cast(float, r);
}
__device__ __forceinline__ float rowmax16(float x) {
  x = fmaxf(x, dppf<0xB1>(x));   // quad_perm xor1
  x = fmaxf(x, dppf<0x4E>(x));   // quad_perm xor2
  x = fmaxf(x, dppf<0x141>(x));  // row_half_mirror
  x = fmaxf(x, dppf<0x140>(x));  // row_mirror
  return x;
}
__device__ __forceinline__ float rowsum16(float x) {
  x += dppf<0xB1>(x);
  x += dppf<0x4E>(x);
  x += dppf<0x141>(x);
  x += dppf<0x140>(x);
  return x;
}

__device__ __forceinline__ bf16x8 cvt8(float4 a, float4 b) {
  bf16x8 r;
  r[0] = (__bf16)a.x; r[1] = (__bf16)a.y; r[2] = (__bf16)a.z; r[3] = (__bf16)a.w;
  r[4] = (__bf16)b.x; r[5] = (__bf16)b.y; r[6] = (__bf16)b.z; r[7] = (__bf16)b.w;
  return r;
}

// Flash attention fwd. fp32 I/O, bf16 MFMA compute.
// 256 threads = 4 waves; wave owns 16 Q rows (Q-tile 64); K-tile 64.
// Single-buffered K/V in LDS (40 KB total) -> 3 blocks/CU = 12 waves/CU.
__global__ __launch_bounds__(256, 3)
void flash_fwd(const float* __restrict__ qg, const float* __restrict__ kg,
               const float* __restrict__ vg, const int* __restrict__ vlg,
               float* __restrict__ og)
{
  // K tile (bf16): 64 rows x 128 d, granule(8)-XOR: (row,g) at row*128+((g^(row&15))<<3)
  __shared__ __align__(16) u16 sK[64 * 128];
  // V tile (bf16) d-major: 128 d x 64 kv: (d,kv) at d*64+(((kv>>3)^(d&7))<<3)+(kv&7)
  __shared__ __align__(16) u16 sV[128 * 64];
  // P per wave: 16 rows x 64, granule-XOR: (row,c) at row*64+((((c>>3)^(row&7))<<3))+(c&7)
  __shared__ __align__(16) u16 sP[4][16 * 64];

  const int tid  = threadIdx.x;
  const int lane = tid & 63;
  const int wv   = tid >> 6;     // wave 0..3
  const int n    = lane & 15;
  const int quad = lane >> 4;

  const int bi = blockIdx.x;
  // XCD-swizzle: same (bi&7) -> same XCD -> 2 batches/XCD worth of K/V locality
  const int b  = ((bi & 7) << 1) | (bi >> 8);
  const int qt = (bi >> 3) & 31;

  const int vl = vlg[b];
  const int nt = (vl + 63) >> 6;

  const int qrow0 = qt * 64 + wv * 16;

  // Q fragments (A-layout: A[m=lane&15][k=quad*8+j]), live whole loop
  bf16x8 qf[4];
  #pragma unroll
  for (int c = 0; c < 4; ++c) {
    const float* qp = qg + (size_t)(b * NQ + qrow0 + n) * ND + c * 32 + quad * 8;
    qf[c] = cvt8(*(const float4*)qp, *(const float4*)(qp + 4));
  }

  f32x4 O[8];
  float mst[4], lst[4];
  #pragma unroll
  for (int f = 0; f < 8; ++f) O[f] = (f32x4){0.f, 0.f, 0.f, 0.f};
  #pragma unroll
  for (int r = 0; r < 4; ++r) { mst[r] = -__builtin_inff(); lst[r] = 0.f; }

  const float* kb = kg + (size_t)(b * NK) * ND;
  const float* vb = vg + (size_t)(b * NK) * ND;

  // Staging: thread owns row srow (0..63), col-quarter scq (32 cols)
  const int srow = tid >> 2, scq = tid & 3;
  bf16x8 kreg[4], vreg[4];

  auto kload = [&](int t) {
    const float* src = kb + (size_t)(t * 64 + srow) * ND + scq * 32;
    #pragma unroll
    for (int c = 0; c < 4; ++c)
      kreg[c] = cvt8(*(const float4*)(src + c * 8), *(const float4*)(src + c * 8 + 4));
  };
  auto kstore = [&]() {
    #pragma unroll
    for (int c = 0; c < 4; ++c) {
      B8 tt; tt.v = kreg[c];
      *(uint4*)(&sK[srow * 128 + (((scq * 4 + c) ^ (srow & 15)) << 3)]) = tt.u;
    }
  };
  auto vload = [&](int t) {
    const float* src = vb + (size_t)(t * 64 + srow) * ND + scq * 32;
    #pragma unroll
    for (int c = 0; c < 4; ++c)
      vreg[c] = cvt8(*(const float4*)(src + c * 8), *(const float4*)(src + c * 8 + 4));
  };
  auto vstore = [&]() {    // transpose-scatter: kv = srow, d = scq*32+c*8+j (d&7 == j)
    #pragma unroll
    for (int c = 0; c < 4; ++c) {
      B8 x; x.v = vreg[c];
      U8 tt; tt.u = x.u;
      #pragma unroll
      for (int j = 0; j < 8; ++j) {
        int d = scq * 32 + c * 8 + j;
        sV[d * 64 + (((srow >> 3) ^ j) << 3) + (srow & 7)] = tt.s[j];
      }
    }
  };

  kload(0); vload(0);
  kstore(); vstore();

  constexpr float CEXP = 0.08838834764831845f * 1.44269504088896340f; // log2e/sqrt(128)

  u16* Pw = sP[wv];

  for (int t = 0; t < nt; ++t) {
    __syncthreads();                   // barrier1: tile t K/V visible in LDS
    if (t + 1 < nt) { kload(t + 1); vload(t + 1); }  // global->regs, overlaps compute

    // ---- S = Q * K^T  (16 MFMAs, 16 b128 reads) ----
    f32x4 S[4];
    #pragma unroll
    for (int jn = 0; jn < 4; ++jn) S[jn] = (f32x4){0.f, 0.f, 0.f, 0.f};
    #pragma unroll
    for (int c = 0; c < 4; ++c)
      #pragma unroll
      for (int jn = 0; jn < 4; ++jn) {
        B8 bb;   // B-frag: K[col=jn*16+n][d=c*32+quad*8+j], unswizzle (row&15 == n)
        bb.u = *(const uint4*)(&sK[(jn * 16 + n) * 128 + (((c * 4 + quad) ^ n) << 3)]);
        S[jn] = __builtin_amdgcn_mfma_f32_16x16x32_bf16(qf[c], bb.v, S[jn], 0, 0, 0);
      }

    // ---- mask tail columns (kv >= vl) ----
    if (t * 64 + 64 > vl) {
      #pragma unroll
      for (int jn = 0; jn < 4; ++jn) {
        bool msk = (t * 64 + jn * 16 + n) >= vl;
        #pragma unroll
        for (int r = 0; r < 4; ++r)
          S[jn][r] = msk ? -1e30f : S[jn][r];
      }
    }

    // ---- online softmax (4 independent row-chains r) ----
    float al[4];
    #pragma unroll
    for (int r = 0; r < 4; ++r) {
      float mx = fmaxf(fmaxf(S[0][r], S[1][r]), fmaxf(S[2][r], S[3][r]));
      mx = rowmax16(mx);
      float mnew = fmaxf(mst[r], mx);
      float a = __builtin_exp2f((mst[r] - mnew) * CEXP);
      mst[r] = mnew;
      float ssum = 0.f;
      #pragma unroll
      for (int jn = 0; jn < 4; ++jn) {
        float p = __builtin_exp2f((S[jn][r] - mnew) * CEXP);
        S[jn][r] = p;
        ssum += p;
      }
      ssum = rowsum16(ssum);
      lst[r] = lst[r] * a + ssum;
      al[r] = a;
    }
    #pragma unroll
    for (int f = 0; f < 8; ++f) {
      O[f][0] *= al[0]; O[f][1] *= al[1]; O[f][2] *= al[2]; O[f][3] *= al[3];
    }

    // P (C-layout) -> per-wave LDS (granule-XOR); same-wave DS order guarantees RAW
    #pragma unroll
    for (int jn = 0; jn < 4; ++jn)
      #pragma unroll
      for (int r = 0; r < 4; ++r) {
        int row = quad * 4 + r;
        __bf16 h = (__bf16)S[jn][r];
        Pw[row * 64 + (((jn * 2 + (n >> 3)) ^ (row & 7)) << 3) + (n & 7)]
            = __builtin_bit_cast(u16, h);
      }

    // ---- O += P * V  (16 MFMAs, 2+16 b128 reads) ----
    #pragma unroll
    for (int kc = 0; kc < 2; ++kc) {
      B8 ta;   // A-frag: P[m=n][k=kc*32+quad*8+j]
      ta.u = *(const uint4*)(&Pw[n * 64 + (((kc * 4 + quad) ^ (n & 7)) << 3)]);
      bf16x8 af = ta.v;
      #pragma unroll
      for (int f = 0; f < 8; ++f) {
        int d = f * 16 + n;                 // d&7 == n&7
        B8 bb;   // B-frag: V[k=kv][n=d] from d-major sV, unswizzle
        bb.u = *(const uint4*)(&sV[d * 64 + (((kc * 4 + quad) ^ (n & 7)) << 3)]);
        O[f] = __builtin_amdgcn_mfma_f32_16x16x32_bf16(af, bb.v, O[f], 0, 0, 0);
      }
    }

    __syncthreads();                   // barrier2: all waves done reading tile t
    if (t + 1 < nt) { kstore(); vstore(); }   // regs -> LDS for tile t+1
  }

  // ---- epilogue: O / l, store fp32 ----
  #pragma unroll
  for (int r = 0; r < 4; ++r) {
    float rl = 1.0f / lst[r];
    int qrow = qrow0 + quad * 4 + r;
    float* op = og + (size_t)(b * NQ + qrow) * ND + n;
    #pragma unroll
    for (int f = 0; f < 8; ++f)
      op[f * 16] = O[f][r] * rl;
  }
}

extern "C" void kernel_launch(void* const* d_in, const int* in_sizes, int n_in,
                              void* d_out, int out_size, void* d_ws, size_t ws_size,
                              hipStream_t stream) {
  const float* q  = (const float*)d_in[0];
  const float* k  = (const float*)d_in[1];
  const float* v  = (const float*)d_in[2];
  const int*  vl  = (const int*)d_in[3];
  float* out = (float*)d_out;
  (void)d_ws; (void)ws_size;

  hipLaunchKernelGGL(flash_fwd, dim3(512), dim3(256), 0, stream, q, k, v, vl, out);
}